// Round 16
// baseline (133.072 us; speedup 1.0000x reference)
//
#include <hip/hip_runtime.h>

// Convoluzione: VALID 3x3 cross-correlation, NCHW.
// img [32,128,56,56] f32, filtro [256,128,3,3] f32 -> out [32,256,54,54] f32
// R16: R12's proven compute core (128co x 8r x 56c, 512thr, phase-buffered
//      filters, img dbuf) with prep_img FUSED into conv: phase A issues per-site
//      f32 loads (coalesced, lane-sweeps x), phase B converts f32->bf16 (RNE,
//      bit-identical to old prep) + ds_write_b128 into the next img buffer.
//      Kills prep_img's 77MB HBM + one launch (~15us wall). DPP reverted (R15
//      proved it neutral). prep_flt (1.2MB) kept.

#define BB   32
#define CIN  128
#define COUT 256
#define HH   56
#define WW   56
#define OH   54
#define OW   54
#define HW   3136                 // HH*WW

typedef short bf16x8 __attribute__((ext_vector_type(8)));
typedef float f32x4  __attribute__((ext_vector_type(4)));
typedef unsigned short u16x8 __attribute__((ext_vector_type(8)));

#define GLOAD_LDS16(g, l) __builtin_amdgcn_global_load_lds( \
    (const __attribute__((address_space(1))) unsigned int*)(g), \
    (__attribute__((address_space(3))) unsigned int*)(l), 16, 0, 0)

static __device__ __forceinline__ unsigned short f2bf(float f) {
    unsigned int u = __float_as_uint(f);
    u += 0x7FFFu + ((u >> 16) & 1u);
    return (unsigned short)(u >> 16);
}

// ---- prep: filtro f32 OIHW -> filtG[cot2][c4][t9][kg4][col128][e8] bf16 ----
// co = cot*128 + col; ci = c*32 + kg*8 + e. Single bf16 (RNE). (R12 verbatim)
__global__ __launch_bounds__(256) void prep_flt(const float* __restrict__ flt,
                                                unsigned short* __restrict__ filtG) {
    const int idx = blockIdx.x * 256 + threadIdx.x;   // 0..32767
    const int co = idx >> 7;
    const int ci = idx & 127;
    const int cot = co >> 7, col = co & 127;
    const int c = ci >> 5, kg = (ci >> 3) & 3, e = ci & 7;
    const size_t base = (size_t)(cot * 4 + c) * 36864 + kg * 1024 + col * 8 + e;
    #pragma unroll
    for (int t = 0; t < 9; ++t)
        filtG[base + t * 4096] = f2bf(flt[(size_t)(co * CIN + ci) * 9 + t]);
}

// ---------------- conv kernel ----------------------------------------------
// 512 thr / 8 waves, 1 block/CU. Tile: 128co x 8rows x 56cols.
// wave = (ch = w>>2 co-half, rp = w&3 rowpair). Per wave: cf4 x xo7, acc 112.
// LDS: img 2 bufs x [kg4][row10][col56]x16B = 71680
//      fltA (taps0-4) [slot5][kg4][col128]x16B = 40960  @71680
//      fltB (taps5-8) [slot4][kg4][col128]x16B = 32768  @112640   tot 145408
#define IMG_ROWB  896
#define IMG_PLANE 8960
#define IMG_BUF   35840
#define FLTA_OFF  71680
#define FLTB_OFF  112640
#define LDS_BYTES 145408

// compute taps [T0, T0+NT): A from aR (+ slot*8192 + cf*256), B from bBc  (R12)
template<int T0, int NT>
static __device__ __forceinline__ void compute_taps(const char* __restrict__ aR,
                                                    const char* __restrict__ bBc,
                                                    f32x4 (&acc)[4][7]) {
    #pragma unroll
    for (int tt = 0; tt < NT; ++tt) {
        const int t = T0 + tt;
        const int dy = t / 3, dx = t % 3;
        bf16x8 A[4];
        #pragma unroll
        for (int cf = 0; cf < 4; ++cf)
            A[cf] = *(const bf16x8*)(aR + tt * 8192 + cf * 256);
        #pragma unroll
        for (int xo = 0; xo < 7; ++xo) {
            bf16x8 bv = *(const bf16x8*)(bBc + dy * IMG_ROWB + (xo * 8 + dx) * 16);
            #pragma unroll
            for (int cf = 0; cf < 4; ++cf)
                acc[cf][xo] = __builtin_amdgcn_mfma_f32_16x16x32_bf16(A[cf], bv, acc[cf][xo], 0, 0, 0);
        }
    }
}

__global__ __launch_bounds__(512, 1) void conv_fused(
    const float* __restrict__ imgF,
    const unsigned short* __restrict__ filtG,
    float* __restrict__ out)
{
    __shared__ char lds[LDS_BYTES];

    const int tid  = threadIdx.x;
    const int lane = tid & 63, w8 = tid >> 6;
    const int ch   = w8 >> 2, rp = w8 & 3;
    const int sub  = lane & 15, kg = lane >> 4;
    const int sr   = sub >> 3,  sc = sub & 7;

    // XCD swizzle (448 = 8*56), cot fastest -> 2 blocks share img tile in L2
    const int w    = (blockIdx.x & 7) * 56 + (blockIdx.x >> 3);
    const int cot  = w & 1;
    const int rest = w >> 1;
    const int strip = rest % 7;
    const int b     = rest / 7;
    const int co0   = cot * 128;
    const int ystart = (strip < 6) ? strip * 8 : (OH - 8);

    char* const pImg = lds;
    char* const pFA  = lds + FLTA_OFF;
    char* const pFB  = lds + FLTB_OFF;
    const char* bB = pImg + kg * IMG_PLANE + (rp * 2 + sr) * IMG_ROWB + sc * 16;
    const char* aA = pFA + kg * 2048 + (ch * 64 + sub) * 16;
    const char* aB = pFB + kg * 2048 + (ch * 64 + sub) * 16;

    const unsigned short* fsrc = filtG + (size_t)cot * 147456;   // + c*36864

    // ---- fused img staging: thread -> site(s) {tid, tid+512 (tid<48)} ----
    // site s: r = s/56, x = s%56; f32 src elem = b*CIN*HW + (ystart+r)*WW + x
    //         + ci*HW, ci = C*32 + kg*8 + e
    const int s1 = tid;
    const bool has2 = (tid < 48);
    const int s2 = 512 + tid;
    int gb1, gb2;
    {
        const int r = s1 / 56, x = s1 - r * 56;
        gb1 = b * (CIN * HW) + (ystart + r) * WW + x;
    }
    {
        const int r = s2 / 56, x = s2 - r * 56;
        gb2 = b * (CIN * HW) + (ystart + r) * WW + x;
    }

    #define LOADI(cn) do { \
        _Pragma("unroll") \
        for (int q = 0; q < 32; ++q) st1[q] = imgF[gb1 + ((cn) * 32 + q) * HW]; \
        if (has2) { \
            _Pragma("unroll") \
            for (int q = 0; q < 32; ++q) st2[q] = imgF[gb2 + ((cn) * 32 + q) * HW]; \
        } \
    } while (0)
    #define WRITEI(cn) do { \
        char* d_ = pImg + ((cn) & 1) * IMG_BUF; \
        _Pragma("unroll") \
        for (int g_ = 0; g_ < 4; ++g_) { \
            unsigned short h_[8]; \
            _Pragma("unroll") \
            for (int e_ = 0; e_ < 8; ++e_) h_[e_] = f2bf(st1[g_ * 8 + e_]); \
            *(u16x8*)(d_ + g_ * IMG_PLANE + s1 * 16) = *(u16x8*)h_; \
        } \
        if (has2) { \
            _Pragma("unroll") \
            for (int g_ = 0; g_ < 4; ++g_) { \
                unsigned short h_[8]; \
                _Pragma("unroll") \
                for (int e_ = 0; e_ < 8; ++e_) h_[e_] = f2bf(st2[g_ * 8 + e_]); \
                *(u16x8*)(d_ + g_ * IMG_PLANE + s2 * 16) = *(u16x8*)h_; \
            } \
        } \
    } while (0)
    #define STAGE_FA(cn) do { \
        _Pragma("unroll") \
        for (int k = 0; k < 5; ++k) \
            GLOAD_LDS16(fsrc + (cn) * 36864 + (k * 512 + tid) * 8, \
                        pFA + (k * 512 + tid) * 16); \
    } while (0)
    #define STAGE_FB(cn) do { \
        _Pragma("unroll") \
        for (int k = 0; k < 4; ++k) \
            GLOAD_LDS16(fsrc + (cn) * 36864 + 20480 + (k * 512 + tid) * 8, \
                        pFB + (k * 512 + tid) * 16); \
    } while (0)
    #define PHASE_SYNC() do { \
        asm volatile("s_waitcnt vmcnt(0) lgkmcnt(0)" ::: "memory"); \
        __builtin_amdgcn_s_barrier(); \
        __builtin_amdgcn_sched_barrier(0); \
    } while (0)

    f32x4 acc[4][7];
    #pragma unroll
    for (int cf = 0; cf < 4; ++cf)
        #pragma unroll
        for (int xo = 0; xo < 7; ++xo) acc[cf][xo] = (f32x4)0.0f;

    float st1[32], st2[32];

    // prologue: load img(0) f32 -> regs, fltA(0) DMA; cvt+write; publish
    LOADI(0);
    STAGE_FA(0);
    asm volatile("s_waitcnt vmcnt(0)" ::: "memory");
    WRITEI(0);
    PHASE_SYNC();

    // per c-iter (R12 schedule + fused staging):
    //  phase A: issue f32 loads img(C+1); stage fltB(C) DMA; taps 0-4; SYNC
    //  phase B: cvt+write img(C+1); stage fltA(C+1) DMA; taps 5-8; SYNC
    #define CONV_ITER(C) do { \
        if ((C) < 3) LOADI((C) + 1); \
        STAGE_FB(C); \
        { const char* bBc = bB + ((C) & 1) * IMG_BUF; \
          __builtin_amdgcn_s_setprio(1); \
          compute_taps<0, 5>(aA, bBc, acc); \
          __builtin_amdgcn_s_setprio(0); } \
        PHASE_SYNC(); \
        if ((C) < 3) { WRITEI((C) + 1); STAGE_FA((C) + 1); } \
        { const char* bBc = bB + ((C) & 1) * IMG_BUF; \
          __builtin_amdgcn_s_setprio(1); \
          compute_taps<5, 4>(aB, bBc, acc); \
          __builtin_amdgcn_s_setprio(0); } \
        if ((C) < 3) PHASE_SYNC(); \
    } while (0)

    CONV_ITER(0);
    CONV_ITER(1);
    CONV_ITER(2);
    CONV_ITER(3);

    // epilogue: D col=lane&15 -> site (sr,sc), row=kg*4+j -> co  (R12 verbatim)
    const int y = ystart + rp * 2 + sr;
    #pragma unroll
    for (int cf = 0; cf < 4; ++cf) {
        const int cob = co0 + ch * 64 + cf * 16 + kg * 4;
        #pragma unroll
        for (int xo = 0; xo < 7; ++xo) {
            const int x = xo * 8 + sc;
            if (x < OW) {
                float* o = out + ((size_t)(b * COUT + cob) * OH + y) * OW + x;
                #pragma unroll
                for (int j = 0; j < 4; ++j)
                    o[(size_t)j * OH * OW] = acc[cf][xo][j];
            }
        }
    }
}

// ---------------- fp32 fallback (ws too small) ------------------------------
#define COB  16
#define THF  6
#define CIBF 2
#define IRF  (THF + 2)
__global__ __launch_bounds__(256) void conv3x3_fp32(
    const float* __restrict__ img, const float* __restrict__ flt,
    float* __restrict__ out)
{
    __shared__ float si[CIBF][IRF][WW];
    __shared__ float sf[CIBF][COB][9];
    const int tid = threadIdx.x;
    const int tx  = tid & 63;
    const int tg  = tid >> 6;
    int bid = blockIdx.x;
    const int ytile = bid % (OH / THF);  bid /= (OH / THF);
    const int cob   = bid % (COUT / COB); bid /= (COUT / COB);
    const int b     = bid;
    const int y0  = ytile * THF;
    const int co0 = cob * COB;
    float acc[4][THF];
    #pragma unroll
    for (int c = 0; c < 4; ++c)
        #pragma unroll
        for (int y = 0; y < THF; ++y) acc[c][y] = 0.0f;
    for (int ci0 = 0; ci0 < CIN; ci0 += CIBF) {
        for (int i = tid; i < CIBF * IRF * (WW / 4); i += 256) {
            const int cil = i / (IRF * (WW / 4));
            int rem = i - cil * (IRF * (WW / 4));
            const int r = rem / (WW / 4);
            const int v = rem - r * (WW / 4);
            const float4* src = reinterpret_cast<const float4*>(
                img + (((size_t)b * CIN + (ci0 + cil)) * HH + (y0 + r)) * WW) + v;
            reinterpret_cast<float4*>(&si[cil][r][0])[v] = *src;
        }
        for (int i = tid; i < CIBF * COB * 9; i += 256) {
            const int cil = i / (COB * 9);
            int rem = i - cil * (COB * 9);
            const int col = rem / 9;
            const int e   = rem - col * 9;
            sf[cil][col][e] = flt[(((size_t)(co0 + col)) * CIN + (ci0 + cil)) * 9 + e];
        }
        __syncthreads();
        if (tx < OW) {
            #pragma unroll
            for (int cil = 0; cil < CIBF; ++cil) {
                float f[4][9];
                #pragma unroll
                for (int c = 0; c < 4; ++c)
                    #pragma unroll
                    for (int e = 0; e < 9; ++e) f[c][e] = sf[cil][tg * 4 + c][e];
                float a[IRF][3];
                #pragma unroll
                for (int r = 0; r < IRF; ++r) {
                    a[r][0] = si[cil][r][tx + 0];
                    a[r][1] = si[cil][r][tx + 1];
                    a[r][2] = si[cil][r][tx + 2];
                }
                #pragma unroll
                for (int y = 0; y < THF; ++y)
                    #pragma unroll
                    for (int dy = 0; dy < 3; ++dy)
                        #pragma unroll
                        for (int c = 0; c < 4; ++c)
                            acc[c][y] = fmaf(a[y + dy][0], f[c][dy * 3 + 0],
                                        fmaf(a[y + dy][1], f[c][dy * 3 + 1],
                                        fmaf(a[y + dy][2], f[c][dy * 3 + 2], acc[c][y])));
            }
        }
        __syncthreads();
    }
    if (tx < OW) {
        #pragma unroll
        for (int c = 0; c < 4; ++c) {
            const int co = co0 + tg * 4 + c;
            #pragma unroll
            for (int y = 0; y < THF; ++y)
                out[(((size_t)b * COUT + co) * OH + (y0 + y)) * OW + tx] = acc[c][y];
        }
    }
}

extern "C" void kernel_launch(void* const* d_in, const int* in_sizes, int n_in,
                              void* d_out, int out_size, void* d_ws, size_t ws_size,
                              hipStream_t stream) {
    const float* img = (const float*)d_in[0];
    const float* flt = (const float*)d_in[1];
    float* out = (float*)d_out;

    const size_t FILT_BYTES = (size_t)2 * 4 * 36864 * 2;        // 589,824
    if (ws_size < FILT_BYTES) {
        conv3x3_fp32<<<BB * (COUT / COB) * (OH / THF), 256, 0, stream>>>(img, flt, out);
        return;
    }
    unsigned short* filtG = (unsigned short*)d_ws;

    prep_flt<<<(COUT * CIN) / 256, 256, 0, stream>>>(flt, filtG);
    conv_fused<<<2 * 7 * BB, 512, 0, stream>>>(img, filtG, out);   // 448 blocks
}

// Round 17
// 93.326 us; speedup vs baseline: 1.4259x; 1.4259x over previous
//
#include <hip/hip_runtime.h>

// Convoluzione: VALID 3x3 cross-correlation, NCHW.
// img [32,128,56,56] f32, filtro [256,128,3,3] f32 -> out [32,256,54,54] f32
// R17: revert to R12's verified optimum (conv 77us, total 94.6us); R16's
//      fused staging spilled (128-VGPR ceiling, R12 frame uses 124 — no slack).
//      Only change: prep_img + prep_flt merged into ONE dispatch (branch on
//      blockIdx; bodies verbatim) — saves one launch.

#define BB   32
#define CIN  128
#define COUT 256
#define HH   56
#define WW   56
#define OH   54
#define OW   54

typedef short bf16x8 __attribute__((ext_vector_type(8)));
typedef float f32x4  __attribute__((ext_vector_type(4)));
typedef unsigned short u16x8 __attribute__((ext_vector_type(8)));

#define GLOAD_LDS16(g, l) __builtin_amdgcn_global_load_lds( \
    (const __attribute__((address_space(1))) unsigned int*)(g), \
    (__attribute__((address_space(3))) unsigned int*)(l), 16, 0, 0)

static __device__ __forceinline__ unsigned short f2bf(float f) {
    unsigned int u = __float_as_uint(f);
    u += 0x7FFFu + ((u >> 16) & 1u);
    return (unsigned short)(u >> 16);
}

// ---- merged prep: blocks [0,1792): img NCHW f32 -> imgT bf16 [b][y][x][ci];
//      blocks [1792,1920): filtro OIHW f32 -> filtG[cot2][c4][t9][kg4][col128][e8]
__global__ __launch_bounds__(256) void prep_all(const float* __restrict__ img,
                                                const float* __restrict__ flt,
                                                unsigned short* __restrict__ imgT,
                                                unsigned short* __restrict__ filtG) {
    if (blockIdx.x < BB * HH) {
        const int b = blockIdx.x / HH;
        const int y = blockIdx.x - b * HH;
        for (int i = threadIdx.x; i < 16 * WW; i += 256) {
            const int g = i / WW;
            const int x = i - g * WW;
            unsigned short pk[8];
            #pragma unroll
            for (int j = 0; j < 8; ++j)
                pk[j] = f2bf(img[((size_t)(b * CIN + g * 8 + j) * HH + y) * WW + x]);
            *(u16x8*)(imgT + ((size_t)(b * HH + y) * WW + x) * CIN + g * 8) = *(u16x8*)pk;
        }
    } else {
        const int idx = (blockIdx.x - BB * HH) * 256 + threadIdx.x;  // 0..32767
        const int co = idx >> 7;
        const int ci = idx & 127;
        const int cot = co >> 7, col = co & 127;
        const int c = ci >> 5, kg = (ci >> 3) & 3, e = ci & 7;
        const size_t base = (size_t)(cot * 4 + c) * 36864 + kg * 1024 + col * 8 + e;
        #pragma unroll
        for (int t = 0; t < 9; ++t)
            filtG[base + t * 4096] = f2bf(flt[(size_t)(co * CIN + ci) * 9 + t]);
    }
}

// ---------------- conv kernel (R12 verbatim) --------------------------------
// 512 thr / 8 waves, 1 block/CU. Tile: 128co x 8rows x 56cols.
// wave = (ch = w>>2 co-half, rp = w&3 rowpair). Per wave: cf4 x xo7, acc 112.
// LDS: img 2 bufs x [kg4][row10][col56]x16B = 71680
//      fltA (taps0-4) [slot5][kg4][col128]x16B = 40960  @71680
//      fltB (taps5-8) [slot4][kg4][col128]x16B = 32768  @112640   tot 145408
#define IMG_ROWB  896            // 56*16
#define IMG_PLANE 8960           // 10 rows
#define IMG_BUF   35840          // 4 planes
#define FLTA_OFF  71680
#define FLTB_OFF  112640
#define LDS_BYTES 145408

// compute taps [T0, T0+NT): A from aR (+ slot*8192 + cf*256), B from bBc
template<int T0, int NT>
static __device__ __forceinline__ void compute_taps(const char* __restrict__ aR,
                                                    const char* __restrict__ bBc,
                                                    f32x4 (&acc)[4][7]) {
    #pragma unroll
    for (int tt = 0; tt < NT; ++tt) {
        const int t = T0 + tt;
        const int dy = t / 3, dx = t % 3;
        bf16x8 A[4];
        #pragma unroll
        for (int cf = 0; cf < 4; ++cf)
            A[cf] = *(const bf16x8*)(aR + tt * 8192 + cf * 256);
        #pragma unroll
        for (int xo = 0; xo < 7; ++xo) {
            bf16x8 bv = *(const bf16x8*)(bBc + dy * IMG_ROWB + (xo * 8 + dx) * 16);
            #pragma unroll
            for (int cf = 0; cf < 4; ++cf)
                acc[cf][xo] = __builtin_amdgcn_mfma_f32_16x16x32_bf16(A[cf], bv, acc[cf][xo], 0, 0, 0);
        }
    }
}

__global__ __launch_bounds__(512, 1) void conv_mfma(
    const unsigned short* __restrict__ imgT,
    const unsigned short* __restrict__ filtG,
    float* __restrict__ out)
{
    __shared__ char lds[LDS_BYTES];

    const int tid  = threadIdx.x;
    const int lane = tid & 63, w8 = tid >> 6;
    const int ch   = w8 >> 2, rp = w8 & 3;
    const int sub  = lane & 15, kg = lane >> 4;
    const int sr   = sub >> 3,  sc = sub & 7;

    // XCD swizzle (448 = 8*56), cot fastest -> 2 blocks share img tile in L2
    const int w    = (blockIdx.x & 7) * 56 + (blockIdx.x >> 3);
    const int cot  = w & 1;
    const int rest = w >> 1;
    const int strip = rest % 7;
    const int b     = rest / 7;
    const int co0   = cot * 128;
    const int ystart = (strip < 6) ? strip * 8 : (OH - 8);

    char* const pImg = lds;
    char* const pFA  = lds + FLTA_OFF;
    char* const pFB  = lds + FLTB_OFF;
    const char* bB = pImg + kg * IMG_PLANE + (rp * 2 + sr) * IMG_ROWB + sc * 16;
    const char* aA = pFA + kg * 2048 + (ch * 64 + sub) * 16;
    const char* aB = pFB + kg * 2048 + (ch * 64 + sub) * 16;

    // filter staging: linear sites (k*512 + tid) x 16B from per-(cot,c) block
    const unsigned short* fsrc = filtG + (size_t)cot * 147456;   // + c*36864 elems

    // img staging: 256-thread half-groups; hs = plane parity, 560 sites/plane
    const int hs = tid >> 8, t8 = tid & 255;
    int goffI[3];
    #pragma unroll
    for (int k = 0; k < 3; ++k) {
        const int s = k * 256 + t8;
        const int r = s / 56;
        const int x = s - r * 56;
        goffI[k] = ((b * HH + ystart + r) * WW + x) * CIN + hs * 8;
    }
    const bool act2 = (t8 < 48);   // site k=2 valid (560 = 2*256 + 48)

    #define STAGE_FA(cn) do { \
        _Pragma("unroll") \
        for (int k = 0; k < 5; ++k) \
            GLOAD_LDS16(fsrc + (cn) * 36864 + (k * 512 + tid) * 8, \
                        pFA + (k * 512 + tid) * 16); \
    } while (0)
    #define STAGE_FB(cn) do { \
        _Pragma("unroll") \
        for (int k = 0; k < 4; ++k) \
            GLOAD_LDS16(fsrc + (cn) * 36864 + 20480 + (k * 512 + tid) * 8, \
                        pFB + (k * 512 + tid) * 16); \
    } while (0)
    #define STAGE_I01(cn) do { \
        char* d_ = pImg + ((cn) & 1) * IMG_BUF + hs * IMG_PLANE; \
        _Pragma("unroll") \
        for (int k = 0; k < 3; ++k) \
            if (k < 2 || act2) \
                GLOAD_LDS16(imgT + goffI[k] + (cn) * 32, d_ + (k * 256 + t8) * 16); \
    } while (0)
    #define STAGE_I23(cn) do { \
        char* d_ = pImg + ((cn) & 1) * IMG_BUF + (2 + hs) * IMG_PLANE; \
        _Pragma("unroll") \
        for (int k = 0; k < 3; ++k) \
            if (k < 2 || act2) \
                GLOAD_LDS16(imgT + goffI[k] + (cn) * 32 + 16, d_ + (k * 256 + t8) * 16); \
    } while (0)
    #define PHASE_SYNC() do { \
        asm volatile("s_waitcnt vmcnt(0) lgkmcnt(0)" ::: "memory"); \
        __builtin_amdgcn_s_barrier(); \
        __builtin_amdgcn_sched_barrier(0); \
    } while (0)

    f32x4 acc[4][7];
    #pragma unroll
    for (int cf = 0; cf < 4; ++cf)
        #pragma unroll
        for (int xo = 0; xo < 7; ++xo) acc[cf][xo] = (f32x4)0.0f;

    // prologue: fltA(0) + img(0) all planes
    STAGE_FA(0);
    STAGE_I01(0);
    STAGE_I23(0);
    PHASE_SYNC();

    #define CONV_ITER(C) do { \
        /* phase A: taps 0-4; stage fltB(C) + img-planes01(C+1) */ \
        STAGE_FB(C); \
        if ((C) < 3) STAGE_I01((C) + 1); \
        { const char* bBc = bB + ((C) & 1) * IMG_BUF; \
          __builtin_amdgcn_s_setprio(1); \
          compute_taps<0, 5>(aA, bBc, acc); \
          __builtin_amdgcn_s_setprio(0); } \
        PHASE_SYNC(); \
        /* phase B: taps 5-8; stage fltA(C+1) + img-planes23(C+1) */ \
        if ((C) < 3) { STAGE_FA((C) + 1); STAGE_I23((C) + 1); } \
        { const char* bBc = bB + ((C) & 1) * IMG_BUF; \
          __builtin_amdgcn_s_setprio(1); \
          compute_taps<5, 4>(aB, bBc, acc); \
          __builtin_amdgcn_s_setprio(0); } \
        if ((C) < 3) PHASE_SYNC(); \
    } while (0)

    CONV_ITER(0);
    CONV_ITER(1);
    CONV_ITER(2);
    CONV_ITER(3);

    // epilogue: D col=lane&15 -> site (sr,sc), row=kg*4+j -> co
    const int y = ystart + rp * 2 + sr;
    #pragma unroll
    for (int cf = 0; cf < 4; ++cf) {
        const int cob = co0 + ch * 64 + cf * 16 + kg * 4;
        #pragma unroll
        for (int xo = 0; xo < 7; ++xo) {
            const int x = xo * 8 + sc;
            if (x < OW) {
                float* o = out + ((size_t)(b * COUT + cob) * OH + y) * OW + x;
                #pragma unroll
                for (int j = 0; j < 4; ++j)
                    o[(size_t)j * OH * OW] = acc[cf][xo][j];
            }
        }
    }
}

// ---------------- fp32 fallback (ws too small) ------------------------------
#define COB  16
#define THF  6
#define CIBF 2
#define IRF  (THF + 2)
__global__ __launch_bounds__(256) void conv3x3_fp32(
    const float* __restrict__ img, const float* __restrict__ flt,
    float* __restrict__ out)
{
    __shared__ float si[CIBF][IRF][WW];
    __shared__ float sf[CIBF][COB][9];
    const int tid = threadIdx.x;
    const int tx  = tid & 63;
    const int tg  = tid >> 6;
    int bid = blockIdx.x;
    const int ytile = bid % (OH / THF);  bid /= (OH / THF);
    const int cob   = bid % (COUT / COB); bid /= (COUT / COB);
    const int b     = bid;
    const int y0  = ytile * THF;
    const int co0 = cob * COB;
    float acc[4][THF];
    #pragma unroll
    for (int c = 0; c < 4; ++c)
        #pragma unroll
        for (int y = 0; y < THF; ++y) acc[c][y] = 0.0f;
    for (int ci0 = 0; ci0 < CIN; ci0 += CIBF) {
        for (int i = tid; i < CIBF * IRF * (WW / 4); i += 256) {
            const int cil = i / (IRF * (WW / 4));
            int rem = i - cil * (IRF * (WW / 4));
            const int r = rem / (WW / 4);
            const int v = rem - r * (WW / 4);
            const float4* src = reinterpret_cast<const float4*>(
                img + (((size_t)b * CIN + (ci0 + cil)) * HH + (y0 + r)) * WW) + v;
            reinterpret_cast<float4*>(&si[cil][r][0])[v] = *src;
        }
        for (int i = tid; i < CIBF * COB * 9; i += 256) {
            const int cil = i / (COB * 9);
            int rem = i - cil * (COB * 9);
            const int col = rem / 9;
            const int e   = rem - col * 9;
            sf[cil][col][e] = flt[(((size_t)(co0 + col)) * CIN + (ci0 + cil)) * 9 + e];
        }
        __syncthreads();
        if (tx < OW) {
            #pragma unroll
            for (int cil = 0; cil < CIBF; ++cil) {
                float f[4][9];
                #pragma unroll
                for (int c = 0; c < 4; ++c)
                    #pragma unroll
                    for (int e = 0; e < 9; ++e) f[c][e] = sf[cil][tg * 4 + c][e];
                float a[IRF][3];
                #pragma unroll
                for (int r = 0; r < IRF; ++r) {
                    a[r][0] = si[cil][r][tx + 0];
                    a[r][1] = si[cil][r][tx + 1];
                    a[r][2] = si[cil][r][tx + 2];
                }
                #pragma unroll
                for (int y = 0; y < THF; ++y)
                    #pragma unroll
                    for (int dy = 0; dy < 3; ++dy)
                        #pragma unroll
                        for (int c = 0; c < 4; ++c)
                            acc[c][y] = fmaf(a[y + dy][0], f[c][dy * 3 + 0],
                                        fmaf(a[y + dy][1], f[c][dy * 3 + 1],
                                        fmaf(a[y + dy][2], f[c][dy * 3 + 2], acc[c][y])));
            }
        }
        __syncthreads();
    }
    if (tx < OW) {
        #pragma unroll
        for (int c = 0; c < 4; ++c) {
            const int co = co0 + tg * 4 + c;
            #pragma unroll
            for (int y = 0; y < THF; ++y)
                out[(((size_t)b * COUT + co) * OH + (y0 + y)) * OW + tx] = acc[c][y];
        }
    }
}

extern "C" void kernel_launch(void* const* d_in, const int* in_sizes, int n_in,
                              void* d_out, int out_size, void* d_ws, size_t ws_size,
                              hipStream_t stream) {
    const float* img = (const float*)d_in[0];
    const float* flt = (const float*)d_in[1];
    float* out = (float*)d_out;

    const size_t IMGT_BYTES = (size_t)BB * HH * WW * CIN * 2;   // 25,690,112
    const size_t FILT_BYTES = (size_t)2 * 4 * 36864 * 2;        //     589,824
    if (ws_size < IMGT_BYTES + FILT_BYTES) {
        conv3x3_fp32<<<BB * (COUT / COB) * (OH / THF), 256, 0, stream>>>(img, flt, out);
        return;
    }
    unsigned short* imgT  = (unsigned short*)d_ws;
    unsigned short* filtG = (unsigned short*)((char*)d_ws + IMGT_BYTES);

    prep_all<<<BB * HH + 128, 256, 0, stream>>>(img, flt, imgT, filtG);
    conv_mfma<<<2 * 7 * BB, 512, 0, stream>>>(imgT, filtG, out);   // 448 blocks
}